// Round 7
// baseline (78.662 us; speedup 1.0000x reference)
//
#include <hip/hip_runtime.h>

// ROIAlign (FPN, multi-level) for MI355X.
// Inputs (f32): fm2 [4,256,256,256] s4 | fm3 [4,128,128,256] s8
//               fm4 [4,64,64,256] s16  | fm5 [4,32,32,256] s32
//               rois [4,512,4] (x1,y1,x2,y2)
// Output (f32): [4,512,256,7,7]
//
// R6 -> R7: occupancy push (latency-bound diagnosis). R6 was capped at
// ~16 waves/CU by VGPR (~90: 16 float4 in flight + weights/addrs in VGPR)
// and 52 KB LDS. Now: (a) wave-uniform weights/offsets/mask hoisted to
// SGPR via readfirstlane, loads shrunk to float2 (32 VGPR payload),
// launch_bounds(512,8) forces VGPR<=64 -> 8 waves/SIMD; (b) channels
// processed in two 128-ch phases over one 25 KB f32 tile -> 4 blocks/CU.
// Target: 32 waves/CU to hide L2-miss gather latency. Bytes unchanged.

constexpr int S     = 7;
constexpr int SS    = 49;
constexpr int CCH   = 256;
constexpr int HCH   = 128;   // channels per phase
constexpr int NROI  = 512;
constexpr int BATCH = 4;

__device__ __forceinline__ float rflf(float x) {
    return __int_as_float(__builtin_amdgcn_readfirstlane(__float_as_int(x)));
}
__device__ __forceinline__ unsigned rflu(unsigned x) {
    return (unsigned)__builtin_amdgcn_readfirstlane((int)x);
}

__global__ __launch_bounds__(512, 8) void roialign_kernel(
    const float* __restrict__ fm2, const float* __restrict__ fm3,
    const float* __restrict__ fm4, const float* __restrict__ fm5,
    const float* __restrict__ rois, float* __restrict__ out)
{
    __shared__ float    tile[SS * HCH];   // 25088 B, XOR-swizzled channel idx
    __shared__ float    s_wyh[14], s_wyl[14], s_wxh[14], s_wxl[14];
    __shared__ unsigned s_ry0[14], s_ry1[14], s_cx0[14], s_cx1[14];
    __shared__ float    s_bw[SS][4];      // merged row weights per bin
    __shared__ float    s_bu[SS][4];      // merged col weights per bin
    __shared__ unsigned s_bm[SS];         // survive mask: rows b0-3, cols b4-7

    const int roi = blockIdx.x;           // 0 .. B*N-1
    const int b   = roi >> 9;

    // ---- wave-uniform prologue ----
    const float x1  = rois[roi * 4 + 0];
    const float y1v = rois[roi * 4 + 1];
    const float x2  = rois[roi * 4 + 2];
    const float y2v = rois[roi * 4 + 3];

    const float area = (y2v - y1v) * (x2 - x1);
    const float lraw = logf(sqrtf(area) * (1.0f / 224.0f)) * 1.4426950408889634f + 4.0f;
    int lvl = (int)rintf(lraw);
    lvl = lvl < 2 ? 2 : (lvl > 5 ? 5 : lvl);

    const float* fm; int H; float scale;
    if (lvl == 2)      { fm = fm2; H = 256; scale = 0.25f;    }
    else if (lvl == 3) { fm = fm3; H = 128; scale = 0.125f;   }
    else if (lvl == 4) { fm = fm4; H = 64;  scale = 0.0625f;  }
    else               { fm = fm5; H = 32;  scale = 0.03125f; }
    const int W = H;
    fm += (size_t)b * H * W * CCH;

    const float bx1 = x1 * scale, by1 = y1v * scale;
    const float rw  = fmaxf(x2 * scale - bx1, 1.0f);
    const float rh  = fmaxf(y2v * scale - by1, 1.0f);
    const float stx = rw * (1.0f / 7.0f);
    const float sty = rh * (1.0f / 7.0f);

    const int t = threadIdx.x;

    // ---- sample LUT: 14 y entries (wave 0) + 14 x entries (wave 1) ----
    if (t < 14) {
        const int k = t;
        const float yy = by1 + ((float)k + 0.5f) * 0.5f * sty;
        const float Hf = (float)H;
        const bool  v  = (yy > -1.0f) && (yy < Hf);
        const float yc = fminf(fmaxf(yy, 0.0f), Hf - 1.0f);
        const int   y0 = (int)floorf(yc);
        const int   y1i = min(y0 + 1, H - 1);
        const float ly = yc - (float)y0;
        s_wyl[k] = v ? ly : 0.0f;
        s_wyh[k] = v ? 1.0f - ly : 0.0f;
        s_ry0[k] = (unsigned)(y0  * W * (CCH * 4));   // byte offset of fm row
        s_ry1[k] = (unsigned)(y1i * W * (CCH * 4));
    } else if (t >= 64 && t < 78) {
        const int k = t - 64;
        const float xx = bx1 + ((float)k + 0.5f) * 0.5f * stx;
        const float Wf = (float)W;
        const bool  v  = (xx > -1.0f) && (xx < Wf);
        const float xc = fminf(fmaxf(xx, 0.0f), Wf - 1.0f);
        const int   x0 = (int)floorf(xc);
        const int   x1i = min(x0 + 1, W - 1);
        const float lx = xc - (float)x0;
        s_wxl[k] = v ? lx : 0.0f;
        s_wxh[k] = v ? 1.0f - lx : 0.0f;
        s_cx0[k] = (unsigned)(x0  * (CCH * 4));       // byte offset of fm col
        s_cx1[k] = (unsigned)(x1i * (CCH * 4));
    }
    __syncthreads();

    // ---- per-bin merged weights + survive mask (one thread per bin) ----
    if (t < SS) {
        const int sy = t / 7, sx = t - sy * 7;
        const int ky = sy << 1, kx = sx << 1;

        float w0 = s_wyh[ky], w1 = s_wyl[ky], w2 = s_wyh[ky + 1], w3 = s_wyl[ky + 1];
        {
            const unsigned rA = s_ry0[ky], rB = s_ry1[ky];
            const unsigned rC = s_ry0[ky + 1], rD = s_ry1[ky + 1];
            const bool eBA = (rB == rA);
            if (eBA) { w0 += w1; w1 = 0.f; }
            const bool eCA = (rC == rA);
            const bool eCB = !eCA && (rC == rB);
            if (eCA) w0 += w2; else if (eCB) w1 += w2;
            if (eCA || eCB) w2 = 0.f;
            const bool eDA = (rD == rA);
            const bool eDB = !eDA && (rD == rB);
            const bool eDC = !eDA && !eDB && (rD == rC);
            if (eDA) w0 += w3; else if (eDB) w1 += w3; else if (eDC) w2 += w3;
            if (eDA || eDB || eDC) w3 = 0.f;
        }
        float u0 = s_wxh[kx], u1 = s_wxl[kx], u2 = s_wxh[kx + 1], u3 = s_wxl[kx + 1];
        {
            const unsigned cA = s_cx0[kx], cB = s_cx1[kx];
            const unsigned cC = s_cx0[kx + 1], cD = s_cx1[kx + 1];
            const bool eBA = (cB == cA);
            if (eBA) { u0 += u1; u1 = 0.f; }
            const bool eCA = (cC == cA);
            const bool eCB = !eCA && (cC == cB);
            if (eCA) u0 += u2; else if (eCB) u1 += u2;
            if (eCA || eCB) u2 = 0.f;
            const bool eDA = (cD == cA);
            const bool eDB = !eDA && (cD == cB);
            const bool eDC = !eDA && !eDB && (cD == cC);
            if (eDA) u0 += u3; else if (eDB) u1 += u3; else if (eDC) u2 += u3;
            if (eDA || eDB || eDC) u3 = 0.f;
        }
        s_bw[t][0] = w0; s_bw[t][1] = w1; s_bw[t][2] = w2; s_bw[t][3] = w3;
        s_bu[t][0] = u0; s_bu[t][1] = u1; s_bu[t][2] = u2; s_bu[t][3] = u3;
        s_bm[t] = (w0 != 0.f ? 0x01u : 0u) | (w1 != 0.f ? 0x02u : 0u)
                | (w2 != 0.f ? 0x04u : 0u) | (w3 != 0.f ? 0x08u : 0u)
                | (u0 != 0.f ? 0x10u : 0u) | (u1 != 0.f ? 0x20u : 0u)
                | (u2 != 0.f ? 0x40u : 0u) | (u3 != 0.f ? 0x80u : 0u);
    }
    __syncthreads();

    // ---- compute: two 128-channel phases; one bin per wave-pass;
    //      2 channels (float2) per lane; uniforms hoisted to SGPR ----
    const int lane = t & 63;
    const int wv   = t >> 6;                       // 0..7
    const char* __restrict__ fmb = (const char*)fm;
    const float2 z2 = make_float2(0.f, 0.f);

    for (int half = 0; half < 2; ++half) {
        const unsigned cb = (unsigned)((half << 9) + (lane << 3)); // byte off in pixel

        for (int bin = wv; bin < SS; bin += 8) {
            const int sy = bin / 7;
            const int sx = bin - sy * 7;
            const int ky = sy << 1, kx = sx << 1;

            // all wave-uniform -> SGPR
            const unsigned m  = rflu(s_bm[bin]);
            const float w0 = rflf(s_bw[bin][0]), w1 = rflf(s_bw[bin][1]);
            const float w2 = rflf(s_bw[bin][2]), w3 = rflf(s_bw[bin][3]);
            const float u0 = rflf(s_bu[bin][0]), u1 = rflf(s_bu[bin][1]);
            const float u2 = rflf(s_bu[bin][2]), u3 = rflf(s_bu[bin][3]);
            const unsigned rA = rflu(s_ry0[ky]),     rB = rflu(s_ry1[ky]);
            const unsigned rC = rflu(s_ry0[ky + 1]), rD = rflu(s_ry1[ky + 1]);
            const unsigned cA = rflu(s_cx0[kx]),     cB = rflu(s_cx1[kx]);
            const unsigned cC = rflu(s_cx0[kx + 1]), cD = rflu(s_cx1[kx + 1]);

#define LD2(OFF) (*(const float2*)(fmb + (OFF)))
            float2 f00 = z2, f01 = z2, f02 = z2, f03 = z2;
            float2 f10 = z2, f11 = z2, f12 = z2, f13 = z2;
            float2 f20 = z2, f21 = z2, f22 = z2, f23 = z2;
            float2 f30 = z2, f31 = z2, f32 = z2, f33 = z2;

            if ((m & 0x11u) == 0x11u) f00 = LD2(rA + cA + cb);
            if ((m & 0x21u) == 0x21u) f01 = LD2(rA + cB + cb);
            if ((m & 0x41u) == 0x41u) f02 = LD2(rA + cC + cb);
            if ((m & 0x81u) == 0x81u) f03 = LD2(rA + cD + cb);
            if ((m & 0x12u) == 0x12u) f10 = LD2(rB + cA + cb);
            if ((m & 0x22u) == 0x22u) f11 = LD2(rB + cB + cb);
            if ((m & 0x42u) == 0x42u) f12 = LD2(rB + cC + cb);
            if ((m & 0x82u) == 0x82u) f13 = LD2(rB + cD + cb);
            if ((m & 0x14u) == 0x14u) f20 = LD2(rC + cA + cb);
            if ((m & 0x24u) == 0x24u) f21 = LD2(rC + cB + cb);
            if ((m & 0x44u) == 0x44u) f22 = LD2(rC + cC + cb);
            if ((m & 0x84u) == 0x84u) f23 = LD2(rC + cD + cb);
            if ((m & 0x18u) == 0x18u) f30 = LD2(rD + cA + cb);
            if ((m & 0x28u) == 0x28u) f31 = LD2(rD + cB + cb);
            if ((m & 0x48u) == 0x48u) f32 = LD2(rD + cC + cb);
            if ((m & 0x88u) == 0x88u) f33 = LD2(rD + cD + cb);
#undef LD2
            __builtin_amdgcn_sched_barrier(0);   // keep loads batched above FMAs

            float2 acc = z2;
#define ACC2(Wt, F) { const float pw_ = (Wt); \
            acc.x = fmaf(pw_, (F).x, acc.x); acc.y = fmaf(pw_, (F).y, acc.y); }
            ACC2(w0 * u0, f00); ACC2(w0 * u1, f01); ACC2(w0 * u2, f02); ACC2(w0 * u3, f03);
            ACC2(w1 * u0, f10); ACC2(w1 * u1, f11); ACC2(w1 * u2, f12); ACC2(w1 * u3, f13);
            ACC2(w2 * u0, f20); ACC2(w2 * u1, f21); ACC2(w2 * u2, f22); ACC2(w2 * u3, f23);
            ACC2(w3 * u0, f30); ACC2(w3 * u1, f31); ACC2(w3 * u2, f32); ACC2(w3 * u3, f33);
#undef ACC2

            // tile[bin][c], channel idx XOR-swizzled so writeback's
            // (c fixed, bin varying) reads spread across 16 banks.
            const unsigned csw = ((unsigned)(lane << 1)) ^ (((unsigned)bin & 15u) << 1);
            *(float2*)&tile[bin * HCH + csw] =
                make_float2(acc.x * 0.25f, acc.y * 0.25f);
        }

        __syncthreads();

        // ---- writeback: contiguous 128*49 floats, coalesced float4 stores ----
        float* oreg = out + (size_t)roi * (CCH * SS) + (size_t)half * (HCH * SS);
        for (int i = t; i < (HCH * SS) / 4; i += 512) {
            const int f0 = i * 4;
            float4 v;
            {
                const int f = f0 + 0;
                const int c = f / SS, bn = f - c * SS;
                v.x = tile[bn * HCH + (c ^ (((unsigned)bn & 15u) << 1))];
            }
            {
                const int f = f0 + 1;
                const int c = f / SS, bn = f - c * SS;
                v.y = tile[bn * HCH + (c ^ (((unsigned)bn & 15u) << 1))];
            }
            {
                const int f = f0 + 2;
                const int c = f / SS, bn = f - c * SS;
                v.z = tile[bn * HCH + (c ^ (((unsigned)bn & 15u) << 1))];
            }
            {
                const int f = f0 + 3;
                const int c = f / SS, bn = f - c * SS;
                v.w = tile[bn * HCH + (c ^ (((unsigned)bn & 15u) << 1))];
            }
            *(float4*)(oreg + f0) = v;
        }

        __syncthreads();   // tile reused by next phase
    }
}

extern "C" void kernel_launch(void* const* d_in, const int* in_sizes, int n_in,
                              void* d_out, int out_size, void* d_ws, size_t ws_size,
                              hipStream_t stream) {
    const float* fm2  = (const float*)d_in[0];
    const float* fm3  = (const float*)d_in[1];
    const float* fm4  = (const float*)d_in[2];
    const float* fm5  = (const float*)d_in[3];
    const float* rois = (const float*)d_in[4];
    float* out = (float*)d_out;

    roialign_kernel<<<BATCH * NROI, 512, 0, stream>>>(fm2, fm3, fm4, fm5, rois, out);
}